// Round 1
// baseline (158.561 us; speedup 1.0000x reference)
//
#include <hip/hip_runtime.h>

typedef __attribute__((ext_vector_type(8))) short short8;
typedef __attribute__((ext_vector_type(4))) float f32x4;

#define LOG2E 1.4426950408889634f

__device__ __forceinline__ unsigned short f2bf(float f) {
  union { float f; unsigned u; } v; v.f = f;
  unsigned r = v.u + 0x7fffu + ((v.u >> 16) & 1u);
  return (unsigned short)(r >> 16);
}
__device__ __forceinline__ unsigned packbf2(float a, float b) {
  return (unsigned)f2bf(a) | ((unsigned)f2bf(b) << 16);
}
// XOR swizzle spreading 16B chunks across banks; bits 4..6 only (within 128B row)
__device__ __forceinline__ int swz(int row) {
  return ((row & 7) << 4) ^ (((row >> 3) & 3) << 5);
}

__global__ __launch_bounds__(256) void assa_fused(
    const float* __restrict__ Q, const float* __restrict__ K,
    const float* __restrict__ V, const float* __restrict__ A1,
    const float* __restrict__ A2, float* __restrict__ O)
{
  constexpr int L = 2048, H = 16, E = 64, RS = H * E; // row stride 1024 floats

  __shared__ __align__(16) char Kb[64 * 128];   // K tile  [key][e]  bf16, swizzled
  __shared__ __align__(16) char Vb[64 * 128];   // V^T tile [e][key] bf16, swizzled
  __shared__ __align__(16) char Pb[4 * 4096];   // per-wave P_dsa(2KB) + P_ssa(2KB)

  const int t = threadIdx.x;
  const int wv = t >> 6;        // wave 0..3
  const int lane = t & 63;
  const int g = lane >> 4;      // lane group 0..3
  const int c = lane & 15;      // column within group (= q-row index)

  const int q0 = blockIdx.x * 64;
  const int bh = blockIdx.y;
  const int b = bh >> 4;
  const int h = bh & 15;

  const size_t base = (size_t)b * L * RS + (size_t)h * E;
  const float* qb = Q + base;
  const float* kb = K + base;
  const float* vb = V + base;
  float* ob = O + base;

  // blend weights from scalars a1, a2
  const float a1 = A1[0], a2 = A2[0];
  const float am = fmaxf(a1, a2);
  const float e1 = expf(a1 - am), e2 = expf(a2 - am);
  const float alpha1 = e1 / (e1 + e2), alpha2 = e2 / (e1 + e2);

  // Q fragments for this wave's 16 rows, pre-scaled by 1/sqrt(E)=0.125 (exact in bf16)
  // B-operand layout of swapped QK^T: lane holds Q[q=c][e = ks*32 + g*8 + j]
  short8 aq[2];
  {
    const float* qr = qb + (size_t)(q0 + wv * 16 + c) * RS;
    #pragma unroll
    for (int ks = 0; ks < 2; ++ks) {
      const float4 u0 = *(const float4*)(qr + ks * 32 + g * 8);
      const float4 u1 = *(const float4*)(qr + ks * 32 + g * 8 + 4);
      short8 f;
      f[0] = (short)f2bf(u0.x * 0.125f); f[1] = (short)f2bf(u0.y * 0.125f);
      f[2] = (short)f2bf(u0.z * 0.125f); f[3] = (short)f2bf(u0.w * 0.125f);
      f[4] = (short)f2bf(u1.x * 0.125f); f[5] = (short)f2bf(u1.y * 0.125f);
      f[6] = (short)f2bf(u1.z * 0.125f); f[7] = (short)f2bf(u1.w * 0.125f);
      aq[ks] = f;
    }
  }

  // out^T accumulators: od/os[et][r] = out^T[e = et*16 + g*4 + r][q = c]
  const f32x4 zero4 = {0.0f, 0.0f, 0.0f, 0.0f};
  f32x4 od[4], os[4];
  #pragma unroll
  for (int i = 0; i < 4; ++i) { od[i] = zero4; os[i] = zero4; }
  float m_run = -3.0e38f, l_run = 0.0f;

  char* Pd = Pb + wv * 4096;   // P_dsa [q][key] 16x64 bf16
  char* Ps = Pd + 2048;        // P_ssa

  for (int s0 = 0; s0 < L; s0 += 64) {
    // ---- stage K tile: 4 threads/row, 16 floats each ----
    {
      const int key = t >> 2, e0 = (t & 3) * 16;
      const float* kr = kb + (size_t)(s0 + key) * RS + e0;
      const float4 u0 = *(const float4*)(kr);
      const float4 u1 = *(const float4*)(kr + 4);
      const float4 u2 = *(const float4*)(kr + 8);
      const float4 u3 = *(const float4*)(kr + 12);
      short8 h0, h1;
      h0[0] = (short)f2bf(u0.x); h0[1] = (short)f2bf(u0.y);
      h0[2] = (short)f2bf(u0.z); h0[3] = (short)f2bf(u0.w);
      h0[4] = (short)f2bf(u1.x); h0[5] = (short)f2bf(u1.y);
      h0[6] = (short)f2bf(u1.z); h0[7] = (short)f2bf(u1.w);
      h1[0] = (short)f2bf(u2.x); h1[1] = (short)f2bf(u2.y);
      h1[2] = (short)f2bf(u2.z); h1[3] = (short)f2bf(u2.w);
      h1[4] = (short)f2bf(u3.x); h1[5] = (short)f2bf(u3.y);
      h1[6] = (short)f2bf(u3.z); h1[7] = (short)f2bf(u3.w);
      const int off = key * 128 + e0 * 2;
      *(short8*)(Kb + (off ^ swz(key))) = h0;
      *(short8*)(Kb + ((off + 16) ^ swz(key))) = h1;
    }
    // ---- stage V^T tile: thread handles key pair (2p,2p+1) x 8 e's ----
    {
      const int p = t >> 3, e0 = (t & 7) * 8;
      const float* v0 = vb + (size_t)(s0 + 2 * p) * RS + e0;
      const float* v1 = v0 + RS;
      const float4 x0 = *(const float4*)(v0);
      const float4 x1 = *(const float4*)(v0 + 4);
      const float4 y0 = *(const float4*)(v1);
      const float4 y1 = *(const float4*)(v1 + 4);
      const float xs[8] = {x0.x, x0.y, x0.z, x0.w, x1.x, x1.y, x1.z, x1.w};
      const float ys[8] = {y0.x, y0.y, y0.z, y0.w, y1.x, y1.y, y1.z, y1.w};
      #pragma unroll
      for (int j = 0; j < 8; ++j) {
        const int row = e0 + j;
        const int off = row * 128 + 4 * p;
        *(unsigned*)(Vb + (off ^ swz(row))) = packbf2(xs[j], ys[j]);
      }
    }
    __syncthreads();

    // ---- S^T = K . Q^T : acc[kt][r] = S[q=c][key = s0 + kt*16 + g*4 + r] ----
    f32x4 acc[4];
    #pragma unroll
    for (int i = 0; i < 4; ++i) acc[i] = zero4;
    #pragma unroll
    for (int kt = 0; kt < 4; ++kt) {
      const int row = kt * 16 + c;
      #pragma unroll
      for (int ks = 0; ks < 2; ++ks) {
        const short8 kf = *(const short8*)(Kb + ((row * 128 + ks * 64 + g * 16) ^ swz(row)));
        acc[kt] = __builtin_amdgcn_mfma_f32_16x16x32_bf16(kf, aq[ks], acc[kt], 0, 0, 0);
      }
    }

    // ---- online softmax stats for q-row c (reduce across 4 lane-groups) ----
    float pmax = -3.0e38f;
    #pragma unroll
    for (int kt = 0; kt < 4; ++kt) {
      #pragma unroll
      for (int r = 0; r < 4; ++r) pmax = fmaxf(pmax, acc[kt][r]);
    }
    pmax = fmaxf(pmax, __shfl_xor(pmax, 16));
    pmax = fmaxf(pmax, __shfl_xor(pmax, 32));
    const float m_new = fmaxf(m_run, pmax);
    const float corr = exp2f((m_run - m_new) * LOG2E);
    m_run = m_new;
    l_run *= corr;
    #pragma unroll
    for (int i = 0; i < 4; ++i) od[i] *= corr;

    // ---- P tiles: p_dsa = exp(s-m), p_ssa = relu(s)^2; write to LDS [q][key] ----
    float psum = 0.0f;
    #pragma unroll
    for (int kt = 0; kt < 4; ++kt) {
      float pd_[4], ps_[4];
      #pragma unroll
      for (int r = 0; r < 4; ++r) {
        const float s = acc[kt][r];
        const float pdv = exp2f((s - m_new) * LOG2E);
        psum += pdv;
        const float sr = fmaxf(s, 0.0f);
        pd_[r] = pdv;
        ps_[r] = sr * sr;
      }
      const int off = c * 128 + kt * 32 + g * 8;
      *(unsigned*)(Pd + (off ^ swz(c)))       = packbf2(pd_[0], pd_[1]);
      *(unsigned*)(Pd + ((off + 4) ^ swz(c))) = packbf2(pd_[2], pd_[3]);
      *(unsigned*)(Ps + (off ^ swz(c)))       = packbf2(ps_[0], ps_[1]);
      *(unsigned*)(Ps + ((off + 4) ^ swz(c))) = packbf2(ps_[2], ps_[3]);
    }
    psum += __shfl_xor(psum, 16);
    psum += __shfl_xor(psum, 32);
    l_run += psum;

    // ---- PV: out^T += V^T . P^T for both paths ----
    #pragma unroll
    for (int ss = 0; ss < 2; ++ss) {
      const int poff = c * 128 + ss * 64 + g * 16;
      const short8 pdf = *(const short8*)(Pd + (poff ^ swz(c)));
      const short8 psf = *(const short8*)(Ps + (poff ^ swz(c)));
      #pragma unroll
      for (int et = 0; et < 4; ++et) {
        const int vrow = et * 16 + c;
        const short8 vf = *(const short8*)(Vb + ((vrow * 128 + ss * 64 + g * 16) ^ swz(vrow)));
        od[et] = __builtin_amdgcn_mfma_f32_16x16x32_bf16(vf, pdf, od[et], 0, 0, 0);
        os[et] = __builtin_amdgcn_mfma_f32_16x16x32_bf16(vf, psf, os[et], 0, 0, 0);
      }
    }
    __syncthreads();
  }

  // ---- epilogue: out = alpha1*ssa + alpha2*dsa/l ----
  const float inv_l = 1.0f / l_run;
  float* orow = ob + (size_t)(q0 + wv * 16 + c) * RS;
  #pragma unroll
  for (int et = 0; et < 4; ++et) {
    #pragma unroll
    for (int r = 0; r < 4; ++r) {
      orow[et * 16 + g * 4 + r] = alpha1 * os[et][r] + alpha2 * od[et][r] * inv_l;
    }
  }
}

extern "C" void kernel_launch(void* const* d_in, const int* in_sizes, int n_in,
                              void* d_out, int out_size, void* d_ws, size_t ws_size,
                              hipStream_t stream) {
  const float* q = (const float*)d_in[0];
  const float* k = (const float*)d_in[1];
  const float* v = (const float*)d_in[2];
  const float* a1 = (const float*)d_in[3];
  const float* a2 = (const float*)d_in[4];
  float* out = (float*)d_out;

  dim3 grid(32, 32);  // 32 q-tiles of 64 rows x (B*H = 32)
  assa_fused<<<grid, 256, 0, stream>>>(q, k, v, a1, a2, out);
}

// Round 2
// 118.979 us; speedup vs baseline: 1.3327x; 1.3327x over previous
//
#include <hip/hip_runtime.h>
#include <hip/hip_bf16.h>

typedef __attribute__((ext_vector_type(8))) short short8;
typedef __attribute__((ext_vector_type(4))) float f32x4;
typedef __attribute__((ext_vector_type(4))) unsigned uint4v;
typedef __attribute__((ext_vector_type(2))) unsigned uint2v;

#define LOG2E 1.4426950408889634f
#define ILN2SQ 0.4804530139182014f   // (ln2)^2, compensates LOG2E^2 in relu^2 path

__device__ __forceinline__ unsigned packbf2(float a, float b) {
  __hip_bfloat162 h = __float22bfloat162_rn(make_float2(a, b));
  return *reinterpret_cast<unsigned*>(&h);
}
// XOR swizzle spreading 16B chunks across banks; bits 4..6 only (within 128B row)
__device__ __forceinline__ int swz(int row) {
  return ((row & 7) << 4) ^ (((row >> 3) & 3) << 5);
}
__device__ __forceinline__ void gload16(const void* g, void* l) {
  __builtin_amdgcn_global_load_lds(
      (const __attribute__((address_space(1))) unsigned int*)g,
      (__attribute__((address_space(3))) unsigned int*)l, 16, 0, 0);
}

// ---------------- prep: fp32 -> bf16, pre-swizzled global layouts ----------------
// KP  = ws[0..8MB):  [bh][s][128B]          bf16 K rows, 16B chunks XOR-swz by s
// VTP = ws[8MB..16MB): [bh][t][e][128B]     bf16 V^T 64x64 tiles, XOR-swz by e
__global__ __launch_bounds__(256) void assa_prep(
    const float* __restrict__ K, const float* __restrict__ V, char* __restrict__ WS)
{
  constexpr int L = 2048, RS = 1024, E = 64;
  char* KP = WS;
  char* VTP = WS + (size_t)8 * 1024 * 1024;
  __shared__ float tile[64][65];
  const int tid = threadIdx.x;

  if (blockIdx.x < 1024) {
    // ---- K path: thread = quarter row (16 floats) ----
    const int gid = blockIdx.x * 256 + tid;
    const int rid = gid >> 2;            // bh*2048 + s
    const int e0 = (gid & 3) * 16;
    const int bh = rid >> 11, s = rid & 2047;
    const int b = bh >> 4, h = bh & 15;
    const float* kr = K + ((size_t)b * L + s) * RS + h * E + e0;
    const float4 u0 = *(const float4*)(kr);
    const float4 u1 = *(const float4*)(kr + 4);
    const float4 u2 = *(const float4*)(kr + 8);
    const float4 u3 = *(const float4*)(kr + 12);
    uint4v w0, w1;
    w0[0] = packbf2(u0.x, u0.y); w0[1] = packbf2(u0.z, u0.w);
    w0[2] = packbf2(u1.x, u1.y); w0[3] = packbf2(u1.z, u1.w);
    w1[0] = packbf2(u2.x, u2.y); w1[1] = packbf2(u2.z, u2.w);
    w1[2] = packbf2(u3.x, u3.y); w1[3] = packbf2(u3.z, u3.w);
    char* dst = KP + (size_t)rid * 128;
    const int sz = swz(s);
    *(uint4v*)(dst + ((e0 * 2) ^ sz)) = w0;
    *(uint4v*)(dst + ((e0 * 2 + 16) ^ sz)) = w1;
  } else {
    // ---- V path: block = (bh, t); transpose 64x64 via LDS ----
    const int bx = blockIdx.x - 1024;
    const int bh = bx >> 5, t5 = bx & 31;
    const int b = bh >> 4, h = bh & 15;
    const float* vb = V + ((size_t)b * L + t5 * 64) * RS + h * E;
    {
      const int key = tid >> 2, e0 = (tid & 3) * 16;
      const float* vr = vb + (size_t)key * RS + e0;
      const float4 u0 = *(const float4*)(vr);
      const float4 u1 = *(const float4*)(vr + 4);
      const float4 u2 = *(const float4*)(vr + 8);
      const float4 u3 = *(const float4*)(vr + 12);
      float* tr = &tile[key][e0];
      tr[0] = u0.x; tr[1] = u0.y; tr[2] = u0.z; tr[3] = u0.w;
      tr[4] = u1.x; tr[5] = u1.y; tr[6] = u1.z; tr[7] = u1.w;
      tr[8] = u2.x; tr[9] = u2.y; tr[10] = u2.z; tr[11] = u2.w;
      tr[12] = u3.x; tr[13] = u3.y; tr[14] = u3.z; tr[15] = u3.w;
    }
    __syncthreads();
    const int e = tid >> 2, k0 = (tid & 3) * 16;
    uint4v w0, w1;
    #pragma unroll
    for (int j = 0; j < 4; ++j)
      w0[j] = packbf2(tile[k0 + 2 * j][e], tile[k0 + 2 * j + 1][e]);
    #pragma unroll
    for (int j = 0; j < 4; ++j)
      w1[j] = packbf2(tile[k0 + 8 + 2 * j][e], tile[k0 + 9 + 2 * j][e]);
    char* dst = VTP + ((size_t)bx * 64 + e) * 128;
    const int sz = swz(e);
    *(uint4v*)(dst + ((k0 * 2) ^ sz)) = w0;
    *(uint4v*)(dst + ((k0 * 2 + 16) ^ sz)) = w1;
  }
}

// ---------------- main fused kernel ----------------
__global__ __launch_bounds__(256) void assa_fused(
    const float* __restrict__ Q, const char* __restrict__ WS,
    const float* __restrict__ A1, const float* __restrict__ A2,
    float* __restrict__ O)
{
  constexpr int L = 2048, H = 16, E = 64, RS = H * E;

  __shared__ __align__(16) char Kb[64 * 128];   // K tile  [key][e]  bf16, swizzled
  __shared__ __align__(16) char Vb[64 * 128];   // V^T tile [e][key] bf16, swizzled
  __shared__ __align__(16) char Pb[4 * 4096];   // per-wave P_dsa(2KB) + P_ssa(2KB)

  const int t = threadIdx.x;
  const int wv = t >> 6;
  const int lane = t & 63;
  const int g = lane >> 4;
  const int c = lane & 15;

  const int q0 = blockIdx.x * 64;
  const int bh = blockIdx.y;
  const int b = bh >> 4;
  const int h = bh & 15;

  const float* qb = Q + (size_t)b * L * RS + (size_t)h * E;
  float* ob = O + (size_t)b * L * RS + (size_t)h * E;
  const char* KP = WS;
  const char* VTP = WS + (size_t)8 * 1024 * 1024;

  const float a1 = A1[0], a2 = A2[0];
  const float am = fmaxf(a1, a2);
  const float e1 = expf(a1 - am), e2 = expf(a2 - am);
  const float alpha1 = (e1 / (e1 + e2)) * ILN2SQ;  // relu^2 path: undo LOG2E^2
  const float alpha2 = e2 / (e1 + e2);

  // Q fragments, pre-scaled by (1/sqrt(E)) * LOG2E so scores are in log2-units
  short8 aq[2];
  {
    const float qs = 0.125f * LOG2E;
    const float* qr = qb + (size_t)(q0 + wv * 16 + c) * RS;
    #pragma unroll
    for (int ks = 0; ks < 2; ++ks) {
      const float4 u0 = *(const float4*)(qr + ks * 32 + g * 8);
      const float4 u1 = *(const float4*)(qr + ks * 32 + g * 8 + 4);
      unsigned p0 = packbf2(u0.x * qs, u0.y * qs);
      unsigned p1 = packbf2(u0.z * qs, u0.w * qs);
      unsigned p2 = packbf2(u1.x * qs, u1.y * qs);
      unsigned p3 = packbf2(u1.z * qs, u1.w * qs);
      short8 f;
      f[0] = (short)(p0 & 0xffff); f[1] = (short)(p0 >> 16);
      f[2] = (short)(p1 & 0xffff); f[3] = (short)(p1 >> 16);
      f[4] = (short)(p2 & 0xffff); f[5] = (short)(p2 >> 16);
      f[6] = (short)(p3 & 0xffff); f[7] = (short)(p3 >> 16);
      aq[ks] = f;
    }
  }

  const f32x4 zero4 = {0.0f, 0.0f, 0.0f, 0.0f};
  f32x4 od[4], os[4];
  #pragma unroll
  for (int i = 0; i < 4; ++i) { od[i] = zero4; os[i] = zero4; }
  float m_run = -3.0e38f, l_run = 0.0f;

  char* Pd = Pb + wv * 4096;
  char* Ps = Pd + 2048;

  // staging pointers: linear copies of pre-swizzled global tiles
  const char* kp_t = KP + (size_t)bh * (2048 * 128) + wv * 1024 + lane * 16;
  const char* vt_t = VTP + (size_t)bh * (32 * 8192) + wv * 1024 + lane * 16;
  char* kd0 = Kb + wv * 1024;
  char* vd0 = Vb + wv * 1024;

  for (int it = 0; it < 32; ++it) {
    gload16(kp_t, kd0);
    gload16(kp_t + 4096, kd0 + 4096);
    gload16(vt_t, vd0);
    gload16(vt_t + 4096, vd0 + 4096);
    kp_t += 8192; vt_t += 8192;
    __syncthreads();   // drains vmcnt -> tiles resident

    // ---- S^T = K . Q^T ----
    f32x4 acc[4];
    #pragma unroll
    for (int i = 0; i < 4; ++i) acc[i] = zero4;
    #pragma unroll
    for (int kt = 0; kt < 4; ++kt) {
      const int row = kt * 16 + c;
      #pragma unroll
      for (int ks = 0; ks < 2; ++ks) {
        const short8 kf = *(const short8*)(Kb + ((row * 128 + ks * 64 + g * 16) ^ swz(row)));
        acc[kt] = __builtin_amdgcn_mfma_f32_16x16x32_bf16(kf, aq[ks], acc[kt], 0, 0, 0);
      }
    }

    // ---- online softmax stats (scores already in log2 units) ----
    float pmax = -3.0e38f;
    #pragma unroll
    for (int kt = 0; kt < 4; ++kt) {
      #pragma unroll
      for (int r = 0; r < 4; ++r) pmax = fmaxf(pmax, acc[kt][r]);
    }
    pmax = fmaxf(pmax, __shfl_xor(pmax, 16));
    pmax = fmaxf(pmax, __shfl_xor(pmax, 32));
    const float m_new = fmaxf(m_run, pmax);
    const float corr = __builtin_amdgcn_exp2f(m_run - m_new);
    m_run = m_new;
    l_run *= corr;
    #pragma unroll
    for (int i = 0; i < 4; ++i) od[i] *= corr;

    // ---- P tiles -> LDS ----
    float psum = 0.0f;
    #pragma unroll
    for (int kt = 0; kt < 4; ++kt) {
      float pd_[4], ps_[4];
      #pragma unroll
      for (int r = 0; r < 4; ++r) {
        const float s = acc[kt][r];
        const float pdv = __builtin_amdgcn_exp2f(s - m_new);
        psum += pdv;
        const float sr = fmaxf(s, 0.0f);
        pd_[r] = pdv;
        ps_[r] = sr * sr;
      }
      const int off = (c * 128 + kt * 32 + g * 8) ^ swz(c);
      uint2v wd; wd[0] = packbf2(pd_[0], pd_[1]); wd[1] = packbf2(pd_[2], pd_[3]);
      uint2v ws2; ws2[0] = packbf2(ps_[0], ps_[1]); ws2[1] = packbf2(ps_[2], ps_[3]);
      *(uint2v*)(Pd + off) = wd;
      *(uint2v*)(Ps + off) = ws2;
    }
    psum += __shfl_xor(psum, 16);
    psum += __shfl_xor(psum, 32);
    l_run += psum;

    // ---- PV: out^T += V^T . P^T (both paths) ----
    #pragma unroll
    for (int ss = 0; ss < 2; ++ss) {
      const int poff = (c * 128 + ss * 64 + g * 16) ^ swz(c);
      const short8 pdf = *(const short8*)(Pd + poff);
      const short8 psf = *(const short8*)(Ps + poff);
      #pragma unroll
      for (int et = 0; et < 4; ++et) {
        const int vrow = et * 16 + c;
        const short8 vf = *(const short8*)(Vb + ((vrow * 128 + ss * 64 + g * 16) ^ swz(vrow)));
        od[et] = __builtin_amdgcn_mfma_f32_16x16x32_bf16(vf, pdf, od[et], 0, 0, 0);
        os[et] = __builtin_amdgcn_mfma_f32_16x16x32_bf16(vf, psf, os[et], 0, 0, 0);
      }
    }
    __syncthreads();   // all waves done reading before next tile's loads land
  }

  // ---- epilogue ----
  const float wd = alpha2 / l_run;
  float* orow = ob + (size_t)(q0 + wv * 16 + c) * RS;
  #pragma unroll
  for (int et = 0; et < 4; ++et) {
    float4 o;
    o.x = alpha1 * os[et][0] + wd * od[et][0];
    o.y = alpha1 * os[et][1] + wd * od[et][1];
    o.z = alpha1 * os[et][2] + wd * od[et][2];
    o.w = alpha1 * os[et][3] + wd * od[et][3];
    *(float4*)(orow + et * 16 + g * 4) = o;
  }
}

extern "C" void kernel_launch(void* const* d_in, const int* in_sizes, int n_in,
                              void* d_out, int out_size, void* d_ws, size_t ws_size,
                              hipStream_t stream) {
  const float* q = (const float*)d_in[0];
  const float* k = (const float*)d_in[1];
  const float* v = (const float*)d_in[2];
  const float* a1 = (const float*)d_in[3];
  const float* a2 = (const float*)d_in[4];
  float* out = (float*)d_out;
  char* ws = (char*)d_ws;

  assa_prep<<<2048, 256, 0, stream>>>(k, v, ws);
  dim3 grid(32, 32);  // 32 q-tiles of 64 rows x (B*H = 32)
  assa_fused<<<grid, 256, 0, stream>>>(q, ws, a1, a2, out);
}

// Round 4
// 93.790 us; speedup vs baseline: 1.6906x; 1.2686x over previous
//
#include <hip/hip_runtime.h>
#include <hip/hip_bf16.h>

typedef __attribute__((ext_vector_type(8))) short short8;
typedef __attribute__((ext_vector_type(4))) short short4v;
typedef __attribute__((ext_vector_type(4))) float f32x4;
typedef __attribute__((ext_vector_type(4))) unsigned uint4v;

#define LOG2E 1.4426950408889634f
#define ILN2SQ 0.4804530139182014f   // (ln2)^2, compensates LOG2E^2 in relu^2 path

__device__ __forceinline__ unsigned packbf2(float a, float b) {
  __hip_bfloat162 h = __float22bfloat162_rn(make_float2(a, b));
  return *reinterpret_cast<unsigned*>(&h);
}
// XOR swizzle spreading 16B chunks across banks; bits 4..6 only (within 128B row)
__device__ __forceinline__ int swz(int row) {
  return ((row & 7) << 4) ^ (((row >> 3) & 3) << 5);
}
__device__ __forceinline__ void gload16(const void* g, void* l) {
  __builtin_amdgcn_global_load_lds(
      (const __attribute__((address_space(1))) unsigned int*)g,
      (__attribute__((address_space(3))) unsigned int*)l, 16, 0, 0);
}

// ---------------- prep: fp32 -> bf16, pre-swizzled global layouts ----------------
// KP  = ws[0..8MB):   [bh][s][128B]      bf16 K rows, 16B chunks XOR-swz by s
// VTP = ws[8MB..16MB): [bh][t][e][128B]  bf16 V^T tiles, KEY-PERMUTED within row:
//        byte pos 2*(g*16+kt*4+j) holds V[key=kt*16+g*4+j][e]; XOR-swz by e.
__global__ __launch_bounds__(256) void assa_prep(
    const float* __restrict__ K, const float* __restrict__ V, char* __restrict__ WS)
{
  constexpr int L = 2048, RS = 1024, E = 64;
  char* KP = WS;
  char* VTP = WS + (size_t)8 * 1024 * 1024;
  __shared__ float tile[64][65];
  const int tid = threadIdx.x;

  if (blockIdx.x < 1024) {
    // ---- K path: thread = quarter row (16 floats) ----
    const int gid = blockIdx.x * 256 + tid;
    const int rid = gid >> 2;            // bh*2048 + s
    const int e0 = (gid & 3) * 16;
    const int bh = rid >> 11, s = rid & 2047;
    const int b = bh >> 4, h = bh & 15;
    const float* kr = K + ((size_t)b * L + s) * RS + h * E + e0;
    const float4 u0 = *(const float4*)(kr);
    const float4 u1 = *(const float4*)(kr + 4);
    const float4 u2 = *(const float4*)(kr + 8);
    const float4 u3 = *(const float4*)(kr + 12);
    uint4v w0, w1;
    w0[0] = packbf2(u0.x, u0.y); w0[1] = packbf2(u0.z, u0.w);
    w0[2] = packbf2(u1.x, u1.y); w0[3] = packbf2(u1.z, u1.w);
    w1[0] = packbf2(u2.x, u2.y); w1[1] = packbf2(u2.z, u2.w);
    w1[2] = packbf2(u3.x, u3.y); w1[3] = packbf2(u3.z, u3.w);
    char* dst = KP + (size_t)rid * 128;
    const int sz = swz(s);
    *(uint4v*)(dst + ((e0 * 2) ^ sz)) = w0;
    *(uint4v*)(dst + ((e0 * 2 + 16) ^ sz)) = w1;
  } else {
    // ---- V path: block = (bh, t); transpose 64x64 via LDS, key-permuted write ----
    const int bx = blockIdx.x - 1024;
    const int bh = bx >> 5, t5 = bx & 31;
    const int b = bh >> 4, h = bh & 15;
    const float* vb = V + ((size_t)b * L + t5 * 64) * RS + h * E;
    {
      const int key = tid >> 2, e0 = (tid & 3) * 16;
      const float* vr = vb + (size_t)key * RS + e0;
      const float4 u0 = *(const float4*)(vr);
      const float4 u1 = *(const float4*)(vr + 4);
      const float4 u2 = *(const float4*)(vr + 8);
      const float4 u3 = *(const float4*)(vr + 12);
      float* tr = &tile[key][e0];
      tr[0] = u0.x; tr[1] = u0.y; tr[2] = u0.z; tr[3] = u0.w;
      tr[4] = u1.x; tr[5] = u1.y; tr[6] = u1.z; tr[7] = u1.w;
      tr[8] = u2.x; tr[9] = u2.y; tr[10] = u2.z; tr[11] = u2.w;
      tr[12] = u3.x; tr[13] = u3.y; tr[14] = u3.z; tr[15] = u3.w;
    }
    __syncthreads();
    const int e = tid >> 2, p0 = (tid & 3) * 16;   // positions p0..p0+15
    const int gg = p0 >> 4;                        // = tid&3
    uint4v w0, w1;
    #pragma unroll
    for (int i = 0; i < 4; ++i) {                  // pos pair (p0+2i, p0+2i+1)
      const int pa = 2 * i, pb = 2 * i + 1;        // pos within 16-chunk
      const int k_a = ((pa >> 2) & 3) * 16 + gg * 4 + (pa & 3);
      const int k_b = ((pb >> 2) & 3) * 16 + gg * 4 + (pb & 3);
      w0[i] = packbf2(tile[k_a][e], tile[k_b][e]);
    }
    #pragma unroll
    for (int i = 0; i < 4; ++i) {
      const int pa = 8 + 2 * i, pb = 9 + 2 * i;
      const int k_a = ((pa >> 2) & 3) * 16 + gg * 4 + (pa & 3);
      const int k_b = ((pb >> 2) & 3) * 16 + gg * 4 + (pb & 3);
      w1[i] = packbf2(tile[k_a][e], tile[k_b][e]);
    }
    char* dst = VTP + ((size_t)bx * 64 + e) * 128;
    const int sz = swz(e);
    *(uint4v*)(dst + ((p0 * 2) ^ sz)) = w0;
    *(uint4v*)(dst + ((p0 * 2 + 16) ^ sz)) = w1;
  }
}

// ---------------- main fused kernel ----------------
__global__ __launch_bounds__(256, 4) void assa_fused(
    const float* __restrict__ Q, const char* __restrict__ WS,
    const float* __restrict__ A1, const float* __restrict__ A2,
    float* __restrict__ O)
{
  constexpr int L = 2048, H = 16, E = 64, RS = H * E;

  __shared__ __align__(16) char Kb[2 * 8192];   // K tile double buffer
  __shared__ __align__(16) char Vb[2 * 8192];   // V^T tile double buffer

  const int t = threadIdx.x;
  const int wv = t >> 6;
  const int lane = t & 63;
  const int g = lane >> 4;
  const int c = lane & 15;

  const int bh = blockIdx.x;            // x = bh -> XCD-pinned K/V reuse
  const int q0 = blockIdx.y * 64;
  const int b = bh >> 4;
  const int h = bh & 15;

  const float* qb = Q + (size_t)b * L * RS + (size_t)h * E;
  float* ob = O + (size_t)b * L * RS + (size_t)h * E;
  const char* KP = WS;
  const char* VTP = WS + (size_t)8 * 1024 * 1024;

  const float a1 = A1[0], a2 = A2[0];
  const float am = fmaxf(a1, a2);
  const float e1 = expf(a1 - am), e2 = expf(a2 - am);
  const float alpha1 = (e1 / (e1 + e2)) * ILN2SQ;  // relu^2 path: undo LOG2E^2
  const float alpha2 = e2 / (e1 + e2);

  // Q fragments, pre-scaled by (1/sqrt(E)) * LOG2E so scores are in log2-units
  short8 aq[2];
  {
    const float qs = 0.125f * LOG2E;
    const float* qr = qb + (size_t)(q0 + wv * 16 + c) * RS;
    #pragma unroll
    for (int ks = 0; ks < 2; ++ks) {
      const float4 u0 = *(const float4*)(qr + ks * 32 + g * 8);
      const float4 u1 = *(const float4*)(qr + ks * 32 + g * 8 + 4);
      unsigned p0 = packbf2(u0.x * qs, u0.y * qs);
      unsigned p1 = packbf2(u0.z * qs, u0.w * qs);
      unsigned p2 = packbf2(u1.x * qs, u1.y * qs);
      unsigned p3 = packbf2(u1.z * qs, u1.w * qs);
      short8 f;
      f[0] = (short)(p0 & 0xffff); f[1] = (short)(p0 >> 16);
      f[2] = (short)(p1 & 0xffff); f[3] = (short)(p1 >> 16);
      f[4] = (short)(p2 & 0xffff); f[5] = (short)(p2 >> 16);
      f[6] = (short)(p3 & 0xffff); f[7] = (short)(p3 >> 16);
      aq[ks] = f;
    }
  }

  // precomputed swizzled LDS byte offsets (within one 8KB half)
  int ka[8];   // K frag reads: [kt][ks]
  #pragma unroll
  for (int kt = 0; kt < 4; ++kt) {
    const int row = kt * 16 + c;
    const int s = swz(row);
    ka[kt * 2 + 0] = (row * 128 + g * 16) ^ s;
    ka[kt * 2 + 1] = (row * 128 + 64 + g * 16) ^ s;
  }
  int va[8];   // V^T frag reads: [et][chunk]  (chunk0 = kt0,1; chunk1 = kt2,3)
  #pragma unroll
  for (int et = 0; et < 4; ++et) {
    const int row = et * 16 + c;
    const int s = swz(row);
    va[et * 2 + 0] = (row * 128 + g * 32) ^ s;
    va[et * 2 + 1] = (row * 128 + g * 32 + 16) ^ s;
  }

  const f32x4 zero4 = {0.0f, 0.0f, 0.0f, 0.0f};
  f32x4 od[4], os[4];
  #pragma unroll
  for (int i = 0; i < 4; ++i) { od[i] = zero4; os[i] = zero4; }
  float psum = 0.0f;

  // staging pointers: linear copies of pre-swizzled global tiles (256KB per bh each)
  const char* kp = KP + (size_t)bh * (2048 * 128) + wv * 1024 + lane * 16;
  const char* vp = VTP + (size_t)bh * (2048 * 128) + wv * 1024 + lane * 16;
  char* kd = Kb + wv * 1024;
  char* vd = Vb + wv * 1024;

#define STAGE(TOFF, HALF)                              \
  do {                                                 \
    gload16(kp + (TOFF), kd + (HALF));                 \
    gload16(kp + (TOFF) + 4096, kd + (HALF) + 4096);   \
    gload16(vp + (TOFF), vd + (HALF));                 \
    gload16(vp + (TOFF) + 4096, vd + (HALF) + 4096);   \
  } while (0)

#define COMPUTE(OFS)                                                                 \
  do {                                                                               \
    f32x4 acc[4];                                                                    \
    _Pragma("unroll")                                                                \
    for (int i = 0; i < 4; ++i) acc[i] = zero4;                                      \
    _Pragma("unroll")                                                                \
    for (int kt = 0; kt < 4; ++kt) {                                                 \
      const short8 kf0 = *(const short8*)(Kb + ka[kt * 2 + 0] + (OFS));              \
      const short8 kf1 = *(const short8*)(Kb + ka[kt * 2 + 1] + (OFS));              \
      acc[kt] = __builtin_amdgcn_mfma_f32_16x16x32_bf16(kf0, aq[0], acc[kt], 0, 0, 0);\
      acc[kt] = __builtin_amdgcn_mfma_f32_16x16x32_bf16(kf1, aq[1], acc[kt], 0, 0, 0);\
    }                                                                                \
    short8 vv[4], vw[4];                                                             \
    _Pragma("unroll")                                                                \
    for (int et = 0; et < 4; ++et) {                                                 \
      vv[et] = *(const short8*)(Vb + va[et * 2 + 0] + (OFS));                        \
      vw[et] = *(const short8*)(Vb + va[et * 2 + 1] + (OFS));                        \
    }                                                                                \
    _Pragma("unroll")                                                                \
    for (int kt = 0; kt < 4; ++kt) {                                                 \
      const float x0 = __builtin_amdgcn_exp2f(acc[kt][0]);                           \
      const float x1 = __builtin_amdgcn_exp2f(acc[kt][1]);                           \
      const float x2 = __builtin_amdgcn_exp2f(acc[kt][2]);                           \
      const float x3 = __builtin_amdgcn_exp2f(acc[kt][3]);                           \
      psum += (x0 + x1) + (x2 + x3);                                                 \
      const float r0 = fmaxf(acc[kt][0], 0.0f), r1 = fmaxf(acc[kt][1], 0.0f);        \
      const float r2 = fmaxf(acc[kt][2], 0.0f), r3 = fmaxf(acc[kt][3], 0.0f);        \
      union { unsigned u[2]; short4v v; } pdu, psu;                                  \
      pdu.u[0] = packbf2(x0, x1); pdu.u[1] = packbf2(x2, x3);                        \
      psu.u[0] = packbf2(r0 * r0, r1 * r1); psu.u[1] = packbf2(r2 * r2, r3 * r3);    \
      const short4v pd = pdu.v, ps = psu.v;                                          \
      _Pragma("unroll")                                                              \
      for (int et = 0; et < 4; ++et) {                                               \
        const short8 vsrc = (kt < 2) ? vv[et] : vw[et];                              \
        short4v vf;                                                                  \
        if (kt & 1) { vf[0] = vsrc[4]; vf[1] = vsrc[5]; vf[2] = vsrc[6]; vf[3] = vsrc[7]; } \
        else        { vf[0] = vsrc[0]; vf[1] = vsrc[1]; vf[2] = vsrc[2]; vf[3] = vsrc[3]; } \
        od[et] = __builtin_amdgcn_mfma_f32_16x16x16bf16_1k(vf, pd, od[et], 0, 0, 0); \
        os[et] = __builtin_amdgcn_mfma_f32_16x16x16bf16_1k(vf, ps, os[et], 0, 0, 0); \
      }                                                                              \
    }                                                                                \
  } while (0)

  STAGE(0, 0);
  __syncthreads();
  size_t toff = 8192;
  for (int it = 0; it < 32; it += 2) {
    STAGE(toff, 8192); toff += 8192;      // tile it+1 -> half1
    COMPUTE(0);
    __syncthreads();
    if (it + 2 < 32) { STAGE(toff, 0); toff += 8192; }   // tile it+2 -> half0
    COMPUTE(8192);
    __syncthreads();
  }
#undef STAGE
#undef COMPUTE

  // ---- final l reduction (per q-row = c, across 4 lane groups) ----
  float l = psum;
  l += __shfl_xor(l, 16);
  l += __shfl_xor(l, 32);

  // ---- epilogue: out[q=c][e=et*16+g*4+r] ----
  const float wd = alpha2 / l;
  float* orow = ob + (size_t)(q0 + wv * 16 + c) * RS;
  #pragma unroll
  for (int et = 0; et < 4; ++et) {
    float4 o;
    o.x = alpha1 * os[et][0] + wd * od[et][0];
    o.y = alpha1 * os[et][1] + wd * od[et][1];
    o.z = alpha1 * os[et][2] + wd * od[et][2];
    o.w = alpha1 * os[et][3] + wd * od[et][3];
    *(float4*)(orow + et * 16 + g * 4) = o;
  }
}

extern "C" void kernel_launch(void* const* d_in, const int* in_sizes, int n_in,
                              void* d_out, int out_size, void* d_ws, size_t ws_size,
                              hipStream_t stream) {
  const float* q = (const float*)d_in[0];
  const float* k = (const float*)d_in[1];
  const float* v = (const float*)d_in[2];
  const float* a1 = (const float*)d_in[3];
  const float* a2 = (const float*)d_in[4];
  float* out = (float*)d_out;
  char* ws = (char*)d_ws;

  assa_prep<<<2048, 256, 0, stream>>>(k, v, ws);
  dim3 grid(32, 32);  // x = bh (XCD-pinned), y = q-tile of 64 rows
  assa_fused<<<grid, 256, 0, stream>>>(q, ws, a1, a2, out);
}

// Round 7
// 89.341 us; speedup vs baseline: 1.7748x; 1.0498x over previous
//
#include <hip/hip_runtime.h>
#include <hip/hip_bf16.h>

typedef __attribute__((ext_vector_type(8))) short short8;
typedef __attribute__((ext_vector_type(4))) short short4v;
typedef __attribute__((ext_vector_type(4))) float f32x4;
typedef __attribute__((ext_vector_type(4))) unsigned uint4v;

#define LOG2E 1.4426950408889634f
#define ILN2SQ 0.4804530139182014f   // (ln2)^2, compensates LOG2E^2 in relu^2 path

// compiler emits v_cvt_pk_bf16_f32 for this (m240: do NOT hand-write the asm)
__device__ __forceinline__ unsigned packbf2(float a, float b) {
  __hip_bfloat162 h = __float22bfloat162_rn(make_float2(a, b));
  return *reinterpret_cast<unsigned*>(&h);
}
// XOR swizzle spreading 16B chunks across banks; bits 4..6 only (within 128B row)
__device__ __forceinline__ int swz(int row) {
  return ((row & 7) << 4) ^ (((row >> 3) & 3) << 5);
}
__device__ __forceinline__ void gload16(const void* g, void* l) {
  __builtin_amdgcn_global_load_lds(
      (const __attribute__((address_space(1))) unsigned int*)g,
      (__attribute__((address_space(3))) unsigned int*)l, 16, 0, 0);
}

// ---------------- prep: fp32 -> bf16, pre-swizzled global layouts ----------------
// KP  = ws[0..8MB):   [bh][s][128B]      bf16 K rows, 16B chunks XOR-swz by s
// VTP = ws[8MB..16MB): [bh][t][e][128B]  bf16 V^T tiles, KEY-PERMUTED within row:
//        byte pos 2*(g*16+kt*4+j) holds V[key=kt*16+g*4+j][e]; XOR-swz by e.
__global__ __launch_bounds__(256) void assa_prep(
    const float* __restrict__ K, const float* __restrict__ V, char* __restrict__ WS)
{
  constexpr int L = 2048, RS = 1024, E = 64;
  char* KP = WS;
  char* VTP = WS + (size_t)8 * 1024 * 1024;
  __shared__ float tile[64][65];
  const int tid = threadIdx.x;

  if (blockIdx.x < 1024) {
    // ---- K path: thread = quarter row (16 floats) ----
    const int gid = blockIdx.x * 256 + tid;
    const int rid = gid >> 2;            // bh*2048 + s
    const int e0 = (gid & 3) * 16;
    const int bh = rid >> 11, s = rid & 2047;
    const int b = bh >> 4, h = bh & 15;
    const float* kr = K + ((size_t)b * L + s) * RS + h * E + e0;
    const float4 u0 = *(const float4*)(kr);
    const float4 u1 = *(const float4*)(kr + 4);
    const float4 u2 = *(const float4*)(kr + 8);
    const float4 u3 = *(const float4*)(kr + 12);
    uint4v w0, w1;
    w0[0] = packbf2(u0.x, u0.y); w0[1] = packbf2(u0.z, u0.w);
    w0[2] = packbf2(u1.x, u1.y); w0[3] = packbf2(u1.z, u1.w);
    w1[0] = packbf2(u2.x, u2.y); w1[1] = packbf2(u2.z, u2.w);
    w1[2] = packbf2(u3.x, u3.y); w1[3] = packbf2(u3.z, u3.w);
    char* dst = KP + (size_t)rid * 128;
    const int sz = swz(s);
    *(uint4v*)(dst + ((e0 * 2) ^ sz)) = w0;
    *(uint4v*)(dst + ((e0 * 2 + 16) ^ sz)) = w1;
  } else {
    // ---- V path: block = (bh, t); transpose 64x64 via LDS, key-permuted write ----
    const int bx = blockIdx.x - 1024;
    const int bh = bx >> 5, t5 = bx & 31;
    const int b = bh >> 4, h = bh & 15;
    const float* vb = V + ((size_t)b * L + t5 * 64) * RS + h * E;
    {
      const int key = tid >> 2, e0 = (tid & 3) * 16;
      const float* vr = vb + (size_t)key * RS + e0;
      const float4 u0 = *(const float4*)(vr);
      const float4 u1 = *(const float4*)(vr + 4);
      const float4 u2 = *(const float4*)(vr + 8);
      const float4 u3 = *(const float4*)(vr + 12);
      float* tr = &tile[key][e0];
      tr[0] = u0.x; tr[1] = u0.y; tr[2] = u0.z; tr[3] = u0.w;
      tr[4] = u1.x; tr[5] = u1.y; tr[6] = u1.z; tr[7] = u1.w;
      tr[8] = u2.x; tr[9] = u2.y; tr[10] = u2.z; tr[11] = u2.w;
      tr[12] = u3.x; tr[13] = u3.y; tr[14] = u3.z; tr[15] = u3.w;
    }
    __syncthreads();
    const int e = tid >> 2, p0 = (tid & 3) * 16;   // positions p0..p0+15
    const int gg = p0 >> 4;                        // = tid&3
    uint4v w0, w1;
    #pragma unroll
    for (int i = 0; i < 4; ++i) {                  // pos pair (p0+2i, p0+2i+1)
      const int pa = 2 * i, pb = 2 * i + 1;
      const int k_a = ((pa >> 2) & 3) * 16 + gg * 4 + (pa & 3);
      const int k_b = ((pb >> 2) & 3) * 16 + gg * 4 + (pb & 3);
      w0[i] = packbf2(tile[k_a][e], tile[k_b][e]);
    }
    #pragma unroll
    for (int i = 0; i < 4; ++i) {
      const int pa = 8 + 2 * i, pb = 9 + 2 * i;
      const int k_a = ((pa >> 2) & 3) * 16 + gg * 4 + (pa & 3);
      const int k_b = ((pb >> 2) & 3) * 16 + gg * 4 + (pb & 3);
      w1[i] = packbf2(tile[k_a][e], tile[k_b][e]);
    }
    char* dst = VTP + ((size_t)bx * 64 + e) * 128;
    const int sz = swz(e);
    *(uint4v*)(dst + ((p0 * 2) ^ sz)) = w0;
    *(uint4v*)(dst + ((p0 * 2 + 16) ^ sz)) = w1;
  }
}

// ---------------- main fused kernel: QBLK=128, 32 q-rows per wave ----------------
__global__ __launch_bounds__(256, 2) void assa_fused(
    const float* __restrict__ Q, const char* __restrict__ WS,
    const float* __restrict__ A1, const float* __restrict__ A2,
    float* __restrict__ O)
{
  constexpr int L = 2048, H = 16, E = 64, RS = H * E;

  __shared__ __align__(16) char Kb[2 * 8192];   // K tile double buffer
  __shared__ __align__(16) char Vb[2 * 8192];   // V^T tile double buffer

  const int t = threadIdx.x;
  const int wv = t >> 6;
  const int lane = t & 63;
  const int g = lane >> 4;
  const int c = lane & 15;

  const int bh = blockIdx.x;            // x = bh -> XCD-pinned K/V reuse
  const int q0 = blockIdx.y * 128;
  const int b = bh >> 4;
  const int h = bh & 15;

  const float* qb = Q + (size_t)b * L * RS + (size_t)h * E;
  float* ob = O + (size_t)b * L * RS + (size_t)h * E;
  const char* KP = WS;
  const char* VTP = WS + (size_t)8 * 1024 * 1024;

  const float a1 = A1[0], a2 = A2[0];
  const float am = fmaxf(a1, a2);
  const float e1 = expf(a1 - am), e2 = expf(a2 - am);
  const float alpha1 = (e1 / (e1 + e2)) * ILN2SQ;  // relu^2 path: undo LOG2E^2
  const float alpha2 = e2 / (e1 + e2);

  // Two Q-row sets per wave: rows q0+wv*32+c (A) and +16 (B).
  // B-frag layout: lane holds Q[q][e = ks*32 + g*8 + j], pre-scaled by 0.125*LOG2E.
  short8 aqA[2], aqB[2];
  {
    const float qs = 0.125f * LOG2E;
    #pragma unroll
    for (int setb = 0; setb < 2; ++setb) {
      const float* qr = qb + (size_t)(q0 + wv * 32 + setb * 16 + c) * RS;
      #pragma unroll
      for (int ks = 0; ks < 2; ++ks) {
        const float4 u0 = *(const float4*)(qr + ks * 32 + g * 8);
        const float4 u1 = *(const float4*)(qr + ks * 32 + g * 8 + 4);
        unsigned p0 = packbf2(u0.x * qs, u0.y * qs);
        unsigned p1 = packbf2(u0.z * qs, u0.w * qs);
        unsigned p2 = packbf2(u1.x * qs, u1.y * qs);
        unsigned p3 = packbf2(u1.z * qs, u1.w * qs);
        short8 f;
        f[0] = (short)(p0 & 0xffff); f[1] = (short)(p0 >> 16);
        f[2] = (short)(p1 & 0xffff); f[3] = (short)(p1 >> 16);
        f[4] = (short)(p2 & 0xffff); f[5] = (short)(p2 >> 16);
        f[6] = (short)(p3 & 0xffff); f[7] = (short)(p3 >> 16);
        if (setb) aqB[ks] = f; else aqA[ks] = f;
      }
    }
  }

  // precomputed swizzled LDS byte offsets (within one 8KB half) — round-4 verbatim
  int ka[8];   // K frag reads: [kt][ks]
  #pragma unroll
  for (int kt = 0; kt < 4; ++kt) {
    const int row = kt * 16 + c;
    const int s = swz(row);
    ka[kt * 2 + 0] = (row * 128 + g * 16) ^ s;
    ka[kt * 2 + 1] = (row * 128 + 64 + g * 16) ^ s;
  }
  int va[8];   // V^T frag reads: [et][chunk]  (chunk0 = kt0,1; chunk1 = kt2,3)
  #pragma unroll
  for (int et = 0; et < 4; ++et) {
    const int row = et * 16 + c;
    const int s = swz(row);
    va[et * 2 + 0] = (row * 128 + g * 32) ^ s;
    va[et * 2 + 1] = (row * 128 + g * 32 + 16) ^ s;
  }

  const f32x4 zero4 = {0.0f, 0.0f, 0.0f, 0.0f};
  f32x4 odA[4], osA[4], odB[4], osB[4];
  #pragma unroll
  for (int i = 0; i < 4; ++i) { odA[i] = zero4; osA[i] = zero4; odB[i] = zero4; osB[i] = zero4; }
  float psumA = 0.0f, psumB = 0.0f;

  // staging pointers: linear copies of pre-swizzled global tiles (256KB per bh each)
  const char* kp = KP + (size_t)bh * (2048 * 128) + wv * 1024 + lane * 16;
  const char* vp = VTP + (size_t)bh * (2048 * 128) + wv * 1024 + lane * 16;
  char* kd = Kb + wv * 1024;
  char* vd = Vb + wv * 1024;

#define STAGE(TOFF, HALF)                              \
  do {                                                 \
    gload16(kp + (TOFF), kd + (HALF));                 \
    gload16(kp + (TOFF) + 4096, kd + (HALF) + 4096);   \
    gload16(vp + (TOFF), vd + (HALF));                 \
    gload16(vp + (TOFF) + 4096, vd + (HALF) + 4096);   \
  } while (0)

#define PROC(ACC, OD, OS, PSUM)                                                      \
  do {                                                                               \
    _Pragma("unroll")                                                                \
    for (int kt = 0; kt < 4; ++kt) {                                                 \
      const float x0 = __builtin_amdgcn_exp2f(ACC[kt][0]);                           \
      const float x1 = __builtin_amdgcn_exp2f(ACC[kt][1]);                           \
      const float x2 = __builtin_amdgcn_exp2f(ACC[kt][2]);                           \
      const float x3 = __builtin_amdgcn_exp2f(ACC[kt][3]);                           \
      PSUM += (x0 + x1) + (x2 + x3);                                                 \
      const float r0 = fmaxf(ACC[kt][0], 0.0f), r1 = fmaxf(ACC[kt][1], 0.0f);        \
      const float r2 = fmaxf(ACC[kt][2], 0.0f), r3 = fmaxf(ACC[kt][3], 0.0f);        \
      union { unsigned u[2]; short4v v; } pdu, psu;                                  \
      pdu.u[0] = packbf2(x0, x1); pdu.u[1] = packbf2(x2, x3);                        \
      psu.u[0] = packbf2(r0 * r0, r1 * r1); psu.u[1] = packbf2(r2 * r2, r3 * r3);    \
      const short4v pd = pdu.v, ps = psu.v;                                          \
      _Pragma("unroll")                                                              \
      for (int et = 0; et < 4; ++et) {                                               \
        const short8 vsrc = (kt < 2) ? vv[et] : vw[et];                              \
        short4v vf;                                                                  \
        if (kt & 1) { vf[0] = vsrc[4]; vf[1] = vsrc[5]; vf[2] = vsrc[6]; vf[3] = vsrc[7]; } \
        else        { vf[0] = vsrc[0]; vf[1] = vsrc[1]; vf[2] = vsrc[2]; vf[3] = vsrc[3]; } \
        OD[et] = __builtin_amdgcn_mfma_f32_16x16x16bf16_1k(vf, pd, OD[et], 0, 0, 0); \
        OS[et] = __builtin_amdgcn_mfma_f32_16x16x16bf16_1k(vf, ps, OS[et], 0, 0, 0); \
      }                                                                              \
    }                                                                                \
  } while (0)

#define COMPUTE(OFS)                                                                 \
  do {                                                                               \
    f32x4 aA[4], aB[4];                                                              \
    _Pragma("unroll")                                                                \
    for (int i = 0; i < 4; ++i) { aA[i] = zero4; aB[i] = zero4; }                    \
    _Pragma("unroll")                                                                \
    for (int kt = 0; kt < 4; ++kt) {                                                 \
      const short8 kf0 = *(const short8*)(Kb + ka[kt * 2 + 0] + (OFS));              \
      const short8 kf1 = *(const short8*)(Kb + ka[kt * 2 + 1] + (OFS));              \
      aA[kt] = __builtin_amdgcn_mfma_f32_16x16x32_bf16(kf0, aqA[0], aA[kt], 0, 0, 0);\
      aA[kt] = __builtin_amdgcn_mfma_f32_16x16x32_bf16(kf1, aqA[1], aA[kt], 0, 0, 0);\
      aB[kt] = __builtin_amdgcn_mfma_f32_16x16x32_bf16(kf0, aqB[0], aB[kt], 0, 0, 0);\
      aB[kt] = __builtin_amdgcn_mfma_f32_16x16x32_bf16(kf1, aqB[1], aB[kt], 0, 0, 0);\
    }                                                                                \
    short8 vv[4], vw[4];                                                             \
    _Pragma("unroll")                                                                \
    for (int et = 0; et < 4; ++et) {                                                 \
      vv[et] = *(const short8*)(Vb + va[et * 2 + 0] + (OFS));                        \
      vw[et] = *(const short8*)(Vb + va[et * 2 + 1] + (OFS));                        \
    }                                                                                \
    PROC(aA, odA, osA, psumA);                                                       \
    PROC(aB, odB, osB, psumB);                                                       \
  } while (0)

  STAGE(0, 0);
  __syncthreads();
  size_t toff = 8192;
  for (int it = 0; it < 32; it += 2) {
    STAGE(toff, 8192); toff += 8192;      // tile it+1 -> half1
    COMPUTE(0);
    __syncthreads();
    if (it + 2 < 32) { STAGE(toff, 0); toff += 8192; }   // tile it+2 -> half0
    COMPUTE(8192);
    __syncthreads();
  }
#undef STAGE
#undef PROC
#undef COMPUTE

  // ---- final l reductions (per q-row = c, across 4 lane groups) ----
  float lA = psumA;
  lA += __shfl_xor(lA, 16);
  lA += __shfl_xor(lA, 32);
  float lB = psumB;
  lB += __shfl_xor(lB, 16);
  lB += __shfl_xor(lB, 32);

  // ---- epilogue: out[q][e=et*16+g*4+r] ----
  const float wdA = alpha2 / lA;
  const float wdB = alpha2 / lB;
  float* orowA = ob + (size_t)(q0 + wv * 32 + c) * RS;
  float* orowB = orowA + (size_t)16 * RS;
  #pragma unroll
  for (int et = 0; et < 4; ++et) {
    float4 oa, obv;
    oa.x = alpha1 * osA[et][0] + wdA * odA[et][0];
    oa.y = alpha1 * osA[et][1] + wdA * odA[et][1];
    oa.z = alpha1 * osA[et][2] + wdA * odA[et][2];
    oa.w = alpha1 * osA[et][3] + wdA * odA[et][3];
    obv.x = alpha1 * osB[et][0] + wdB * odB[et][0];
    obv.y = alpha1 * osB[et][1] + wdB * odB[et][1];
    obv.z = alpha1 * osB[et][2] + wdB * odB[et][2];
    obv.w = alpha1 * osB[et][3] + wdB * odB[et][3];
    *(float4*)(orowA + et * 16 + g * 4) = oa;
    *(float4*)(orowB + et * 16 + g * 4) = obv;
  }
}

extern "C" void kernel_launch(void* const* d_in, const int* in_sizes, int n_in,
                              void* d_out, int out_size, void* d_ws, size_t ws_size,
                              hipStream_t stream) {
  const float* q = (const float*)d_in[0];
  const float* k = (const float*)d_in[1];
  const float* v = (const float*)d_in[2];
  const float* a1 = (const float*)d_in[3];
  const float* a2 = (const float*)d_in[4];
  float* out = (float*)d_out;
  char* ws = (char*)d_ws;

  assa_prep<<<2048, 256, 0, stream>>>(k, v, ws);
  dim3 grid(32, 16);  // x = bh (XCD-pinned), y = q-tile of 128 rows
  assa_fused<<<grid, 256, 0, stream>>>(q, ws, a1, a2, out);
}

// Round 8
// 78.330 us; speedup vs baseline: 2.0243x; 1.1406x over previous
//
#include <hip/hip_runtime.h>
#include <hip/hip_bf16.h>

typedef __attribute__((ext_vector_type(8))) short short8;
typedef __attribute__((ext_vector_type(4))) float f32x4;
typedef __attribute__((ext_vector_type(4))) unsigned uint4v;

#define LOG2E 1.4426950408889634f
#define ILN2SQ 0.4804530139182014f   // (ln2)^2, compensates LOG2E^2 in relu^2 path

// compiler emits v_cvt_pk_bf16_f32 for this (m240: do NOT hand-write the asm)
__device__ __forceinline__ unsigned packbf2(float a, float b) {
  __hip_bfloat162 h = __float22bfloat162_rn(make_float2(a, b));
  return *reinterpret_cast<unsigned*>(&h);
}
// XOR swizzle spreading 16B chunks across banks; bits 4..6 only (within 128B row)
__device__ __forceinline__ int swz(int row) {
  return ((row & 7) << 4) ^ (((row >> 3) & 3) << 5);
}
__device__ __forceinline__ void gload16(const void* g, void* l) {
  __builtin_amdgcn_global_load_lds(
      (const __attribute__((address_space(1))) unsigned int*)g,
      (__attribute__((address_space(3))) unsigned int*)l, 16, 0, 0);
}

// PV key permutation: logical slot p (0..63) within a V^T row maps to physical key
//   R = p>>5, g = (p&31)>>3, jj = p&7  ->  key = (R*2 + (jj>>2))*16 + g*4 + (jj&3)
// so that lane-group g's 16B fragment read delivers keys {kt, g*4 + r} matching the
// lane's own QK^T accumulator scores (B-frag = concat of packed acc, no shuffles).
__device__ __forceinline__ int pv_key(int p) {
  const int R = p >> 5, g = (p & 31) >> 3, jj = p & 7;
  return (R * 2 + (jj >> 2)) * 16 + g * 4 + (jj & 3);
}

// ---------------- prep: fp32 -> bf16, pre-swizzled global layouts ----------------
// KP  = ws[0..8MB):   [bh][s][128B]      bf16 K rows, 16B chunks XOR-swz by s
// VTP = ws[8MB..16MB): [bh][t][e][128B]  bf16 V^T tiles, PV-KEY-PERMUTED within row
//        (byte pos 2*p holds V[pv_key(p)][e]); XOR-swz by e.
__global__ __launch_bounds__(256) void assa_prep(
    const float* __restrict__ K, const float* __restrict__ V, char* __restrict__ WS)
{
  constexpr int L = 2048, RS = 1024, E = 64;
  char* KP = WS;
  char* VTP = WS + (size_t)8 * 1024 * 1024;
  __shared__ float tile[64][65];
  const int tid = threadIdx.x;

  if (blockIdx.x < 1024) {
    // ---- K path: thread = quarter row (16 floats) ----
    const int gid = blockIdx.x * 256 + tid;
    const int rid = gid >> 2;            // bh*2048 + s
    const int e0 = (gid & 3) * 16;
    const int bh = rid >> 11, s = rid & 2047;
    const int b = bh >> 4, h = bh & 15;
    const float* kr = K + ((size_t)b * L + s) * RS + h * E + e0;
    const float4 u0 = *(const float4*)(kr);
    const float4 u1 = *(const float4*)(kr + 4);
    const float4 u2 = *(const float4*)(kr + 8);
    const float4 u3 = *(const float4*)(kr + 12);
    uint4v w0, w1;
    w0[0] = packbf2(u0.x, u0.y); w0[1] = packbf2(u0.z, u0.w);
    w0[2] = packbf2(u1.x, u1.y); w0[3] = packbf2(u1.z, u1.w);
    w1[0] = packbf2(u2.x, u2.y); w1[1] = packbf2(u2.z, u2.w);
    w1[2] = packbf2(u3.x, u3.y); w1[3] = packbf2(u3.z, u3.w);
    char* dst = KP + (size_t)rid * 128;
    const int sz = swz(s);
    *(uint4v*)(dst + ((e0 * 2) ^ sz)) = w0;
    *(uint4v*)(dst + ((e0 * 2 + 16) ^ sz)) = w1;
  } else {
    // ---- V path: block = (bh, t); transpose 64x64 via LDS, pv_key-permuted write ----
    const int bx = blockIdx.x - 1024;
    const int bh = bx >> 5, t5 = bx & 31;
    const int b = bh >> 4, h = bh & 15;
    const float* vb = V + ((size_t)b * L + t5 * 64) * RS + h * E;
    {
      const int key = tid >> 2, e0 = (tid & 3) * 16;
      const float* vr = vb + (size_t)key * RS + e0;
      const float4 u0 = *(const float4*)(vr);
      const float4 u1 = *(const float4*)(vr + 4);
      const float4 u2 = *(const float4*)(vr + 8);
      const float4 u3 = *(const float4*)(vr + 12);
      float* tr = &tile[key][e0];
      tr[0] = u0.x; tr[1] = u0.y; tr[2] = u0.z; tr[3] = u0.w;
      tr[4] = u1.x; tr[5] = u1.y; tr[6] = u1.z; tr[7] = u1.w;
      tr[8] = u2.x; tr[9] = u2.y; tr[10] = u2.z; tr[11] = u2.w;
      tr[12] = u3.x; tr[13] = u3.y; tr[14] = u3.z; tr[15] = u3.w;
    }
    __syncthreads();
    const int e = tid >> 2, p0 = (tid & 3) * 16;   // positions p0..p0+15
    uint4v w0, w1;
    #pragma unroll
    for (int i = 0; i < 4; ++i)
      w0[i] = packbf2(tile[pv_key(p0 + 2 * i)][e], tile[pv_key(p0 + 2 * i + 1)][e]);
    #pragma unroll
    for (int i = 0; i < 4; ++i)
      w1[i] = packbf2(tile[pv_key(p0 + 8 + 2 * i)][e], tile[pv_key(p0 + 9 + 2 * i)][e]);
    char* dst = VTP + ((size_t)bx * 64 + e) * 128;
    const int sz = swz(e);
    *(uint4v*)(dst + ((p0 * 2) ^ sz)) = w0;
    *(uint4v*)(dst + ((p0 * 2 + 16) ^ sz)) = w1;
  }
}

// ---------------- main fused kernel: QBLK=128, 32 q-rows per wave ----------------
__global__ __launch_bounds__(256, 2) void assa_fused(
    const float* __restrict__ Q, const char* __restrict__ WS,
    const float* __restrict__ A1, const float* __restrict__ A2,
    float* __restrict__ O)
{
  constexpr int L = 2048, H = 16, E = 64, RS = H * E;

  __shared__ __align__(16) char Kb[2 * 8192];   // K tile double buffer
  __shared__ __align__(16) char Vb[2 * 8192];   // V^T tile double buffer

  const int t = threadIdx.x;
  const int wv = t >> 6;
  const int lane = t & 63;
  const int g = lane >> 4;
  const int c = lane & 15;

  const int bh = blockIdx.x;            // x = bh -> XCD-pinned K/V reuse
  const int q0 = blockIdx.y * 128;
  const int b = bh >> 4;
  const int h = bh & 15;

  const float* qb = Q + (size_t)b * L * RS + (size_t)h * E;
  float* ob = O + (size_t)b * L * RS + (size_t)h * E;
  const char* KP = WS;
  const char* VTP = WS + (size_t)8 * 1024 * 1024;

  const float a1 = A1[0], a2 = A2[0];
  const float am = fmaxf(a1, a2);
  const float e1 = expf(a1 - am), e2 = expf(a2 - am);
  const float alpha1 = (e1 / (e1 + e2)) * ILN2SQ;  // relu^2 path: undo LOG2E^2
  const float alpha2 = e2 / (e1 + e2);

  // Two Q-row sets per wave: rows q0+wv*32+c (A) and +16 (B).
  // B-frag layout: lane holds Q[q][e = ks*32 + g*8 + j], pre-scaled by 0.125*LOG2E.
  short8 aqA[2], aqB[2];
  {
    const float qs = 0.125f * LOG2E;
    #pragma unroll
    for (int setb = 0; setb < 2; ++setb) {
      const float* qr = qb + (size_t)(q0 + wv * 32 + setb * 16 + c) * RS;
      #pragma unroll
      for (int ks = 0; ks < 2; ++ks) {
        const float4 u0 = *(const float4*)(qr + ks * 32 + g * 8);
        const float4 u1 = *(const float4*)(qr + ks * 32 + g * 8 + 4);
        union { unsigned u[4]; short8 s; } f;
        f.u[0] = packbf2(u0.x * qs, u0.y * qs);
        f.u[1] = packbf2(u0.z * qs, u0.w * qs);
        f.u[2] = packbf2(u1.x * qs, u1.y * qs);
        f.u[3] = packbf2(u1.z * qs, u1.w * qs);
        if (setb) aqB[ks] = f.s; else aqA[ks] = f.s;
      }
    }
  }

  // precomputed swizzled LDS byte offsets (within one 8KB half)
  int ka[8];   // K frag reads: [kt][ks]
  #pragma unroll
  for (int kt = 0; kt < 4; ++kt) {
    const int row = kt * 16 + c;
    const int s = swz(row);
    ka[kt * 2 + 0] = (row * 128 + g * 16) ^ s;
    ka[kt * 2 + 1] = (row * 128 + 64 + g * 16) ^ s;
  }
  int va[8];   // V^T frag reads: [et][tp]  (tp0 = keys kt0/kt1, tp1 = keys kt2/kt3)
  #pragma unroll
  for (int et = 0; et < 4; ++et) {
    const int row = et * 16 + c;
    const int s = swz(row);
    va[et * 2 + 0] = (row * 128 + g * 16) ^ s;
    va[et * 2 + 1] = (row * 128 + 64 + g * 16) ^ s;
  }

  const f32x4 zero4 = {0.0f, 0.0f, 0.0f, 0.0f};
  f32x4 odA[4], osA[4], odB[4], osB[4];
  #pragma unroll
  for (int i = 0; i < 4; ++i) { odA[i] = zero4; osA[i] = zero4; odB[i] = zero4; osB[i] = zero4; }
  float psumA = 0.0f, psumB = 0.0f;

  // staging pointers: linear copies of pre-swizzled global tiles (256KB per bh each)
  const char* kp = KP + (size_t)bh * (2048 * 128) + wv * 1024 + lane * 16;
  const char* vp = VTP + (size_t)bh * (2048 * 128) + wv * 1024 + lane * 16;
  char* kd = Kb + wv * 1024;
  char* vd = Vb + wv * 1024;

  union U8 { unsigned u[4]; short8 s; };

#define STAGE(TOFF, HALF)                              \
  do {                                                 \
    gload16(kp + (TOFF), kd + (HALF));                 \
    gload16(kp + (TOFF) + 4096, kd + (HALF) + 4096);   \
    gload16(vp + (TOFF), vd + (HALF));                 \
    gload16(vp + (TOFF) + 4096, vd + (HALF) + 4096);   \
  } while (0)

#define PROC(ACC, OD, OS, PSUM)                                                      \
  do {                                                                               \
    unsigned pdw[8], psw[8];                                                         \
    _Pragma("unroll")                                                                \
    for (int kt = 0; kt < 4; ++kt) {                                                 \
      const float x0 = __builtin_amdgcn_exp2f(ACC[kt][0]);                           \
      const float x1 = __builtin_amdgcn_exp2f(ACC[kt][1]);                           \
      const float x2 = __builtin_amdgcn_exp2f(ACC[kt][2]);                           \
      const float x3 = __builtin_amdgcn_exp2f(ACC[kt][3]);                           \
      PSUM += (x0 + x1) + (x2 + x3);                                                 \
      const float r0 = fmaxf(ACC[kt][0], 0.0f), r1 = fmaxf(ACC[kt][1], 0.0f);        \
      const float r2 = fmaxf(ACC[kt][2], 0.0f), r3 = fmaxf(ACC[kt][3], 0.0f);        \
      pdw[kt * 2 + 0] = packbf2(x0, x1);                                             \
      pdw[kt * 2 + 1] = packbf2(x2, x3);                                             \
      psw[kt * 2 + 0] = packbf2(r0 * r0, r1 * r1);                                   \
      psw[kt * 2 + 1] = packbf2(r2 * r2, r3 * r3);                                   \
    }                                                                                \
    _Pragma("unroll")                                                                \
    for (int tp = 0; tp < 2; ++tp) {                                                 \
      U8 bpd, bps;                                                                   \
      bpd.u[0] = pdw[tp * 4 + 0]; bpd.u[1] = pdw[tp * 4 + 1];                        \
      bpd.u[2] = pdw[tp * 4 + 2]; bpd.u[3] = pdw[tp * 4 + 3];                        \
      bps.u[0] = psw[tp * 4 + 0]; bps.u[1] = psw[tp * 4 + 1];                        \
      bps.u[2] = psw[tp * 4 + 2]; bps.u[3] = psw[tp * 4 + 3];                        \
      _Pragma("unroll")                                                              \
      for (int et = 0; et < 4; ++et) {                                               \
        const short8 vf = tp ? vfr1[et] : vfr0[et];                                  \
        OD[et] = __builtin_amdgcn_mfma_f32_16x16x32_bf16(vf, bpd.s, OD[et], 0, 0, 0);\
        OS[et] = __builtin_amdgcn_mfma_f32_16x16x32_bf16(vf, bps.s, OS[et], 0, 0, 0);\
      }                                                                              \
    }                                                                                \
  } while (0)

#define COMPUTE(OFS)                                                                 \
  do {                                                                               \
    f32x4 aA[4], aB[4];                                                              \
    _Pragma("unroll")                                                                \
    for (int i = 0; i < 4; ++i) { aA[i] = zero4; aB[i] = zero4; }                    \
    _Pragma("unroll")                                                                \
    for (int kt = 0; kt < 4; ++kt) {                                                 \
      const short8 kf0 = *(const short8*)(Kb + ka[kt * 2 + 0] + (OFS));              \
      const short8 kf1 = *(const short8*)(Kb + ka[kt * 2 + 1] + (OFS));              \
      aA[kt] = __builtin_amdgcn_mfma_f32_16x16x32_bf16(kf0, aqA[0], aA[kt], 0, 0, 0);\
      aA[kt] = __builtin_amdgcn_mfma_f32_16x16x32_bf16(kf1, aqA[1], aA[kt], 0, 0, 0);\
      aB[kt] = __builtin_amdgcn_mfma_f32_16x16x32_bf16(kf0, aqB[0], aB[kt], 0, 0, 0);\
      aB[kt] = __builtin_amdgcn_mfma_f32_16x16x32_bf16(kf1, aqB[1], aB[kt], 0, 0, 0);\
    }                                                                                \
    short8 vfr0[4], vfr1[4];                                                         \
    _Pragma("unroll")                                                                \
    for (int et = 0; et < 4; ++et) {                                                 \
      vfr0[et] = *(const short8*)(Vb + va[et * 2 + 0] + (OFS));                      \
      vfr1[et] = *(const short8*)(Vb + va[et * 2 + 1] + (OFS));                      \
    }                                                                                \
    PROC(aA, odA, osA, psumA);                                                       \
    PROC(aB, odB, osB, psumB);                                                       \
  } while (0)

  STAGE(0, 0);
  __syncthreads();
  size_t toff = 8192;
  for (int it = 0; it < 32; it += 2) {
    STAGE(toff, 8192); toff += 8192;      // tile it+1 -> half1
    COMPUTE(0);
    __syncthreads();
    if (it + 2 < 32) { STAGE(toff, 0); toff += 8192; }   // tile it+2 -> half0
    COMPUTE(8192);
    __syncthreads();
  }
#undef STAGE
#undef PROC
#undef COMPUTE

  // ---- final l reductions (per q-row = c, across 4 lane groups) ----
  float lA = psumA;
  lA += __shfl_xor(lA, 16);
  lA += __shfl_xor(lA, 32);
  float lB = psumB;
  lB += __shfl_xor(lB, 16);
  lB += __shfl_xor(lB, 32);

  // ---- epilogue: out[q][e=et*16+g*4+r] ----
  const float wdA = alpha2 / lA;
  const float wdB = alpha2 / lB;
  float* orowA = ob + (size_t)(q0 + wv * 32 + c) * RS;
  float* orowB = orowA + (size_t)16 * RS;
  #pragma unroll
  for (int et = 0; et < 4; ++et) {
    float4 oa, obv;
    oa.x = alpha1 * osA[et][0] + wdA * odA[et][0];
    oa.y = alpha1 * osA[et][1] + wdA * odA[et][1];
    oa.z = alpha1 * osA[et][2] + wdA * odA[et][2];
    oa.w = alpha1 * osA[et][3] + wdA * odA[et][3];
    obv.x = alpha1 * osB[et][0] + wdB * odB[et][0];
    obv.y = alpha1 * osB[et][1] + wdB * odB[et][1];
    obv.z = alpha1 * osB[et][2] + wdB * odB[et][2];
    obv.w = alpha1 * osB[et][3] + wdB * odB[et][3];
    *(float4*)(orowA + et * 16 + g * 4) = oa;
    *(float4*)(orowB + et * 16 + g * 4) = obv;
  }
}

extern "C" void kernel_launch(void* const* d_in, const int* in_sizes, int n_in,
                              void* d_out, int out_size, void* d_ws, size_t ws_size,
                              hipStream_t stream) {
  const float* q = (const float*)d_in[0];
  const float* k = (const float*)d_in[1];
  const float* v = (const float*)d_in[2];
  const float* a1 = (const float*)d_in[3];
  const float* a2 = (const float*)d_in[4];
  float* out = (float*)d_out;
  char* ws = (char*)d_ws;

  assa_prep<<<2048, 256, 0, stream>>>(k, v, ws);
  dim3 grid(32, 16);  // x = bh (XCD-pinned), y = q-tile of 128 rows
  assa_fused<<<grid, 256, 0, stream>>>(q, ws, a1, a2, out);
}

// Round 9
// 77.169 us; speedup vs baseline: 2.0547x; 1.0150x over previous
//
#include <hip/hip_runtime.h>
#include <hip/hip_bf16.h>

typedef __attribute__((ext_vector_type(8))) short short8;
typedef __attribute__((ext_vector_type(4))) float f32x4;
typedef __attribute__((ext_vector_type(4))) unsigned uint4v;

#define LOG2E 1.4426950408889634f
#define ILN2SQ 0.4804530139182014f   // (ln2)^2, compensates LOG2E^2 in relu^2 path

// compiler emits v_cvt_pk_bf16_f32 for this (m240: do NOT hand-write the asm)
__device__ __forceinline__ unsigned packbf2(float a, float b) {
  __hip_bfloat162 h = __float22bfloat162_rn(make_float2(a, b));
  return *reinterpret_cast<unsigned*>(&h);
}
// XOR swizzle spreading 16B chunks across banks; bits 4..6 only (within 128B row)
__device__ __forceinline__ int swz(int row) {
  return ((row & 7) << 4) ^ (((row >> 3) & 3) << 5);
}
__device__ __forceinline__ void gload16(const void* g, void* l) {
  __builtin_amdgcn_global_load_lds(
      (const __attribute__((address_space(1))) unsigned int*)g,
      (__attribute__((address_space(3))) unsigned int*)l, 16, 0, 0);
}

// PV key permutation: logical slot p (0..63) within a V^T row maps to physical key
//   R = p>>5, g = (p&31)>>3, jj = p&7  ->  key = (R*2 + (jj>>2))*16 + g*4 + (jj&3)
// so that lane-group g's 16B fragment read delivers keys matching the lane's own
// QK^T accumulator scores (B-frag = concat of packed acc, no shuffles).
__device__ __forceinline__ int pv_key(int p) {
  const int R = p >> 5, g = (p & 31) >> 3, jj = p & 7;
  return (R * 2 + (jj >> 2)) * 16 + g * 4 + (jj & 3);
}

// ---------------- prep: fp32 -> bf16, pre-swizzled global layouts ----------------
// KP  = ws[0..8MB):   [bh][s][128B]      bf16 K rows, 16B chunks XOR-swz by s
// VTP = ws[8MB..16MB): [bh][t][e][128B]  bf16 V^T tiles, PV-KEY-PERMUTED within row
//        (byte pos 2*p holds V[pv_key(p)][e]); XOR-swz by e.
__global__ __launch_bounds__(256) void assa_prep(
    const float* __restrict__ K, const float* __restrict__ V, char* __restrict__ WS)
{
  constexpr int L = 2048, RS = 1024, E = 64;
  char* KP = WS;
  char* VTP = WS + (size_t)8 * 1024 * 1024;
  __shared__ float tile[64][65];
  const int tid = threadIdx.x;

  if (blockIdx.x < 1024) {
    // ---- K path: thread = quarter row (16 floats) ----
    const int gid = blockIdx.x * 256 + tid;
    const int rid = gid >> 2;            // bh*2048 + s
    const int e0 = (gid & 3) * 16;
    const int bh = rid >> 11, s = rid & 2047;
    const int b = bh >> 4, h = bh & 15;
    const float* kr = K + ((size_t)b * L + s) * RS + h * E + e0;
    const float4 u0 = *(const float4*)(kr);
    const float4 u1 = *(const float4*)(kr + 4);
    const float4 u2 = *(const float4*)(kr + 8);
    const float4 u3 = *(const float4*)(kr + 12);
    uint4v w0, w1;
    w0[0] = packbf2(u0.x, u0.y); w0[1] = packbf2(u0.z, u0.w);
    w0[2] = packbf2(u1.x, u1.y); w0[3] = packbf2(u1.z, u1.w);
    w1[0] = packbf2(u2.x, u2.y); w1[1] = packbf2(u2.z, u2.w);
    w1[2] = packbf2(u3.x, u3.y); w1[3] = packbf2(u3.z, u3.w);
    char* dst = KP + (size_t)rid * 128;
    const int sz = swz(s);
    *(uint4v*)(dst + ((e0 * 2) ^ sz)) = w0;
    *(uint4v*)(dst + ((e0 * 2 + 16) ^ sz)) = w1;
  } else {
    // ---- V path: block = (bh, t); transpose 64x64 via LDS, pv_key-permuted write ----
    const int bx = blockIdx.x - 1024;
    const int bh = bx >> 5, t5 = bx & 31;
    const int b = bh >> 4, h = bh & 15;
    const float* vb = V + ((size_t)b * L + t5 * 64) * RS + h * E;
    {
      const int key = tid >> 2, e0 = (tid & 3) * 16;
      const float* vr = vb + (size_t)key * RS + e0;
      const float4 u0 = *(const float4*)(vr);
      const float4 u1 = *(const float4*)(vr + 4);
      const float4 u2 = *(const float4*)(vr + 8);
      const float4 u3 = *(const float4*)(vr + 12);
      float* tr = &tile[key][e0];
      tr[0] = u0.x; tr[1] = u0.y; tr[2] = u0.z; tr[3] = u0.w;
      tr[4] = u1.x; tr[5] = u1.y; tr[6] = u1.z; tr[7] = u1.w;
      tr[8] = u2.x; tr[9] = u2.y; tr[10] = u2.z; tr[11] = u2.w;
      tr[12] = u3.x; tr[13] = u3.y; tr[14] = u3.z; tr[15] = u3.w;
    }
    __syncthreads();
    const int e = tid >> 2, p0 = (tid & 3) * 16;   // positions p0..p0+15
    uint4v w0, w1;
    #pragma unroll
    for (int i = 0; i < 4; ++i)
      w0[i] = packbf2(tile[pv_key(p0 + 2 * i)][e], tile[pv_key(p0 + 2 * i + 1)][e]);
    #pragma unroll
    for (int i = 0; i < 4; ++i)
      w1[i] = packbf2(tile[pv_key(p0 + 8 + 2 * i)][e], tile[pv_key(p0 + 9 + 2 * i)][e]);
    char* dst = VTP + ((size_t)bx * 64 + e) * 128;
    const int sz = swz(e);
    *(uint4v*)(dst + ((p0 * 2) ^ sz)) = w0;
    *(uint4v*)(dst + ((p0 * 2 + 16) ^ sz)) = w1;
  }
}

// -------- main fused kernel: QBLK=128, 8 waves x 16 q-rows, 512 threads --------
__global__ __launch_bounds__(512, 4) void assa_fused(
    const float* __restrict__ Q, const char* __restrict__ WS,
    const float* __restrict__ A1, const float* __restrict__ A2,
    float* __restrict__ O)
{
  constexpr int L = 2048, H = 16, E = 64, RS = H * E;

  __shared__ __align__(16) char Kb[2 * 8192];   // K tile double buffer
  __shared__ __align__(16) char Vb[2 * 8192];   // V^T tile double buffer

  const int t = threadIdx.x;
  const int wv = t >> 6;        // wave 0..7
  const int lane = t & 63;
  const int g = lane >> 4;
  const int c = lane & 15;

  const int bh = blockIdx.x;            // x = bh -> XCD-pinned K/V reuse
  const int q0 = blockIdx.y * 128;
  const int b = bh >> 4;
  const int h = bh & 15;

  const float* qb = Q + (size_t)b * L * RS + (size_t)h * E;
  float* ob = O + (size_t)b * L * RS + (size_t)h * E;
  const char* KP = WS;
  const char* VTP = WS + (size_t)8 * 1024 * 1024;

  const float a1 = A1[0], a2 = A2[0];
  const float am = fmaxf(a1, a2);
  const float e1 = expf(a1 - am), e2 = expf(a2 - am);
  const float alpha1 = (e1 / (e1 + e2)) * ILN2SQ;  // relu^2 path: undo LOG2E^2
  const float alpha2 = e2 / (e1 + e2);

  // This wave's 16 q-rows: q0 + wv*16 + c.
  // B-frag layout: lane holds Q[q][e = ks*32 + g*8 + j], pre-scaled by 0.125*LOG2E.
  short8 aq[2];
  {
    const float qs = 0.125f * LOG2E;
    const float* qr = qb + (size_t)(q0 + wv * 16 + c) * RS;
    #pragma unroll
    for (int ks = 0; ks < 2; ++ks) {
      const float4 u0 = *(const float4*)(qr + ks * 32 + g * 8);
      const float4 u1 = *(const float4*)(qr + ks * 32 + g * 8 + 4);
      union { unsigned u[4]; short8 s; } f;
      f.u[0] = packbf2(u0.x * qs, u0.y * qs);
      f.u[1] = packbf2(u0.z * qs, u0.w * qs);
      f.u[2] = packbf2(u1.x * qs, u1.y * qs);
      f.u[3] = packbf2(u1.z * qs, u1.w * qs);
      aq[ks] = f.s;
    }
  }

  // precomputed swizzled LDS byte offsets (within one 8KB half)
  int ka[8];   // K frag reads: [kt][ks]
  #pragma unroll
  for (int kt = 0; kt < 4; ++kt) {
    const int row = kt * 16 + c;
    const int s = swz(row);
    ka[kt * 2 + 0] = (row * 128 + g * 16) ^ s;
    ka[kt * 2 + 1] = (row * 128 + 64 + g * 16) ^ s;
  }
  int va[8];   // V^T frag reads: [et][tp]  (tp0 = keys kt0/kt1, tp1 = keys kt2/kt3)
  #pragma unroll
  for (int et = 0; et < 4; ++et) {
    const int row = et * 16 + c;
    const int s = swz(row);
    va[et * 2 + 0] = (row * 128 + g * 16) ^ s;
    va[et * 2 + 1] = (row * 128 + 64 + g * 16) ^ s;
  }

  const f32x4 zero4 = {0.0f, 0.0f, 0.0f, 0.0f};
  f32x4 od[4], os[4];
  #pragma unroll
  for (int i = 0; i < 4; ++i) { od[i] = zero4; os[i] = zero4; }
  float psum = 0.0f;

  // staging: 512 threads x 16B = one full 8KB tile each for K and V per STAGE
  const char* kp = KP + (size_t)bh * (2048 * 128) + t * 16;
  const char* vp = VTP + (size_t)bh * (2048 * 128) + t * 16;
  char* kd = Kb + wv * 1024 + lane * 16 - lane * 16;   // wave-uniform base
  char* vd = Vb + wv * 1024 + lane * 16 - lane * 16;

  union U8 { unsigned u[4]; short8 s; };

#define STAGE(TOFF, HALF)                              \
  do {                                                 \
    gload16(kp + (TOFF), kd + (HALF));                 \
    gload16(vp + (TOFF), vd + (HALF));                 \
  } while (0)

#define PROC(ACC, OD, OS, PSUM)                                                      \
  do {                                                                               \
    unsigned pdw[8], psw[8];                                                         \
    _Pragma("unroll")                                                                \
    for (int kt = 0; kt < 4; ++kt) {                                                 \
      const float x0 = __builtin_amdgcn_exp2f(ACC[kt][0]);                           \
      const float x1 = __builtin_amdgcn_exp2f(ACC[kt][1]);                           \
      const float x2 = __builtin_amdgcn_exp2f(ACC[kt][2]);                           \
      const float x3 = __builtin_amdgcn_exp2f(ACC[kt][3]);                           \
      PSUM += (x0 + x1) + (x2 + x3);                                                 \
      const float r0 = fmaxf(ACC[kt][0], 0.0f), r1 = fmaxf(ACC[kt][1], 0.0f);        \
      const float r2 = fmaxf(ACC[kt][2], 0.0f), r3 = fmaxf(ACC[kt][3], 0.0f);        \
      pdw[kt * 2 + 0] = packbf2(x0, x1);                                             \
      pdw[kt * 2 + 1] = packbf2(x2, x3);                                             \
      psw[kt * 2 + 0] = packbf2(r0 * r0, r1 * r1);                                   \
      psw[kt * 2 + 1] = packbf2(r2 * r2, r3 * r3);                                   \
    }                                                                                \
    _Pragma("unroll")                                                                \
    for (int tp = 0; tp < 2; ++tp) {                                                 \
      U8 bpd, bps;                                                                   \
      bpd.u[0] = pdw[tp * 4 + 0]; bpd.u[1] = pdw[tp * 4 + 1];                        \
      bpd.u[2] = pdw[tp * 4 + 2]; bpd.u[3] = pdw[tp * 4 + 3];                        \
      bps.u[0] = psw[tp * 4 + 0]; bps.u[1] = psw[tp * 4 + 1];                        \
      bps.u[2] = psw[tp * 4 + 2]; bps.u[3] = psw[tp * 4 + 3];                        \
      _Pragma("unroll")                                                              \
      for (int et = 0; et < 4; ++et) {                                               \
        const short8 vf = tp ? vfr1[et] : vfr0[et];                                  \
        OD[et] = __builtin_amdgcn_mfma_f32_16x16x32_bf16(vf, bpd.s, OD[et], 0, 0, 0);\
        OS[et] = __builtin_amdgcn_mfma_f32_16x16x32_bf16(vf, bps.s, OS[et], 0, 0, 0);\
      }                                                                              \
    }                                                                                \
  } while (0)

#define COMPUTE(OFS)                                                                 \
  do {                                                                               \
    f32x4 acc[4];                                                                    \
    _Pragma("unroll")                                                                \
    for (int i = 0; i < 4; ++i) acc[i] = zero4;                                      \
    _Pragma("unroll")                                                                \
    for (int kt = 0; kt < 4; ++kt) {                                                 \
      const short8 kf0 = *(const short8*)(Kb + ka[kt * 2 + 0] + (OFS));              \
      const short8 kf1 = *(const short8*)(Kb + ka[kt * 2 + 1] + (OFS));              \
      acc[kt] = __builtin_amdgcn_mfma_f32_16x16x32_bf16(kf0, aq[0], acc[kt], 0, 0, 0);\
      acc[kt] = __builtin_amdgcn_mfma_f32_16x16x32_bf16(kf1, aq[1], acc[kt], 0, 0, 0);\
    }                                                                                \
    short8 vfr0[4], vfr1[4];                                                         \
    _Pragma("unroll")                                                                \
    for (int et = 0; et < 4; ++et) {                                                 \
      vfr0[et] = *(const short8*)(Vb + va[et * 2 + 0] + (OFS));                      \
      vfr1[et] = *(const short8*)(Vb + va[et * 2 + 1] + (OFS));                      \
    }                                                                                \
    PROC(acc, od, os, psum);                                                         \
  } while (0)

  STAGE(0, 0);
  __syncthreads();
  size_t toff = 8192;
  for (int it = 0; it < 32; it += 2) {
    STAGE(toff, 8192); toff += 8192;      // tile it+1 -> half1
    COMPUTE(0);
    __syncthreads();
    if (it + 2 < 32) { STAGE(toff, 0); toff += 8192; }   // tile it+2 -> half0
    COMPUTE(8192);
    __syncthreads();
  }
#undef STAGE
#undef PROC
#undef COMPUTE

  // ---- final l reduction (per q-row = c, across 4 lane groups) ----
  float l = psum;
  l += __shfl_xor(l, 16);
  l += __shfl_xor(l, 32);

  // ---- epilogue: out[q][e=et*16+g*4+r] ----
  const float wd = alpha2 / l;
  float* orow = ob + (size_t)(q0 + wv * 16 + c) * RS;
  #pragma unroll
  for (int et = 0; et < 4; ++et) {
    float4 o;
    o.x = alpha1 * os[et][0] + wd * od[et][0];
    o.y = alpha1 * os[et][1] + wd * od[et][1];
    o.z = alpha1 * os[et][2] + wd * od[et][2];
    o.w = alpha1 * os[et][3] + wd * od[et][3];
    *(float4*)(orow + et * 16 + g * 4) = o;
  }
}

extern "C" void kernel_launch(void* const* d_in, const int* in_sizes, int n_in,
                              void* d_out, int out_size, void* d_ws, size_t ws_size,
                              hipStream_t stream) {
  const float* q = (const float*)d_in[0];
  const float* k = (const float*)d_in[1];
  const float* v = (const float*)d_in[2];
  const float* a1 = (const float*)d_in[3];
  const float* a2 = (const float*)d_in[4];
  float* out = (float*)d_out;
  char* ws = (char*)d_ws;

  assa_prep<<<2048, 256, 0, stream>>>(k, v, ws);
  dim3 grid(32, 16);  // x = bh (XCD-pinned), y = q-tile of 128 rows
  assa_fused<<<grid, 512, 0, stream>>>(q, ws, a1, a2, out);
}